// Round 13
// baseline (369.043 us; speedup 1.0000x reference)
//
#include <hip/hip_runtime.h>
#include <cmath>

#define D_IN 512
#define HC   512   // H1*C1 == H2*C2 == D_IN
#define NH1  8
#define NC1  64
#define NH2  4
#define NC2  128
#define GBM 64
#define GBK 32

typedef __attribute__((ext_vector_type(8))) short short8;
typedef __attribute__((ext_vector_type(4))) float f32x4;

__device__ inline ushort f2bf(float f) {
  unsigned u = __float_as_uint(f);
  return (ushort)((u + 0x7FFFu + ((u >> 16) & 1u)) >> 16);
}
__device__ inline float bf2f(ushort b) { return __uint_as_float(((unsigned)b) << 16); }

// ---------- all input casts in one launch ----------------------------------
__global__ void k_cast_all(const float* __restrict__ x, ushort* __restrict__ Abf,
                           const float* __restrict__ W1, const float* __restrict__ W2,
                           ushort* __restrict__ Wt1, ushort* __restrict__ Wt2, int n4x) {
  const int KN = D_IN * HC;
  int i = blockIdx.x * blockDim.x + threadIdx.x;
  if (i < n4x) {
    float4 v = ((const float4*)x)[i];
    ushort4 r = { f2bf(v.x), f2bf(v.y), f2bf(v.z), f2bf(v.w) };
    ((ushort4*)Abf)[i] = r;
  } else {
    int idx = i - n4x;
    if (idx >= 2 * KN) return;
    const float* W = (idx < KN) ? W1 : W2;
    ushort* Wt = (idx < KN) ? Wt1 : Wt2;
    int j = (idx < KN) ? idx : idx - KN;
    int n = j / D_IN, k = j - n * D_IN;
    Wt[j] = f2bf(W[(size_t)k * HC + n]);
  }
}

// ---------- bf16 MFMA GEMM, BM=64 x BN=512 (full N per block) --------------
// A is streamed exactly ONCE (no N-tile refetch); B (0.5 MB) re-read per block
// but L2-resident per XCD. 4 waves: wave w computes rows[all 64] x cols
// [w*128, +128). LDS fragment-order staging via global_load_lds (R11-verified
// conflict-free map): slot s=(rowblk*4+kchunk), addr=(s*16+lane16)*8 ushorts.
// Att epilogue: all heads in-block -> plain stores for BOTH layers.
template<int H>
__global__ __launch_bounds__(256)
void k_gemm_bf16(const ushort* __restrict__ A, const ushort* __restrict__ Bt,
                 ushort* __restrict__ Cbf,
                 const float* __restrict__ att_s, const float* __restrict__ att_d,
                 float* __restrict__ asrc, float* __restrict__ adst, int M) {
  constexpr int C = HC / H;
  constexpr int HG = 128 / C;    // heads per wave: 2 (H=8) or 1 (H=4)
  constexpr int JPH = 8 / HG;    // j-tiles per head: 4 or 8
  __shared__ __align__(16) ushort As[GBM * GBK];   // 4 KB
  __shared__ __align__(16) ushort Bs[512 * GBK];   // 32 KB, 8 regions of 64 rows
  int t = threadIdx.x;
  int m0 = blockIdx.x * GBM;
  int wave = t >> 6, lane = t & 63;
  int ln = lane & 15, qd = lane >> 4;

  f32x4 acc[4][8] = {};

  // staging map: thread t -> row-block g=t>>6, k-chunk ct=(t>>4)&3, row lt=t&15
  int g = t >> 6, ct = (t >> 4) & 3, lt = t & 15;
  int rA = m0 + g * 16 + lt; if (rA > M - 1) rA = M - 1;
  const ushort* gA = A + (size_t)rA * D_IN + ct * 8;
  const ushort* gB = Bt + (size_t)(g * 16 + lt) * D_IN + ct * 8;

  for (int k0 = 0; k0 < D_IN; k0 += GBK) {
    __syncthreads();
    __builtin_amdgcn_global_load_lds(
        (const __attribute__((address_space(1))) void*)(gA + k0),
        (__attribute__((address_space(3))) void*)(As + t * 8), 16, 0, 0);
#pragma unroll
    for (int r = 0; r < 8; ++r)
      __builtin_amdgcn_global_load_lds(
          (const __attribute__((address_space(1))) void*)(gB + (size_t)r * 64 * D_IN + k0),
          (__attribute__((address_space(3))) void*)(Bs + r * 2048 + t * 8), 16, 0, 0);
    __syncthreads();
    short8 a[4], bb[8];
#pragma unroll
    for (int i = 0; i < 4; ++i)
      a[i] = *(const short8*)&As[(i * 4 + qd) * 128 + ln * 8];
#pragma unroll
    for (int j = 0; j < 8; ++j) {
      int col = wave * 128 + j * 16;          // + ln (ln<16 stays in 64-row region)
      int region = col >> 6;
      int rg = (col & 63) >> 4;
      bb[j] = *(const short8*)&Bs[region * 2048 + (rg * 4 + qd) * 128 + ln * 8];
    }
#pragma unroll
    for (int i = 0; i < 4; ++i)
#pragma unroll
      for (int j = 0; j < 8; ++j)
        acc[i][j] = __builtin_amdgcn_mfma_f32_16x16x32_bf16(a[i], bb[j], acc[i][j], 0, 0, 0);
  }

  // ---- C store (C/D layout: col = ln, row = qd*4 + reg) ----
#pragma unroll
  for (int i = 0; i < 4; ++i) {
#pragma unroll
    for (int reg = 0; reg < 4; ++reg) {
      int row = m0 + i * 16 + qd * 4 + reg;
      if (row >= M) continue;
#pragma unroll
      for (int j = 0; j < 8; ++j)
        Cbf[(size_t)row * HC + wave * 128 + j * 16 + ln] = f2bf(acc[i][j][reg]);
    }
  }

  // ---- fused attention scores (plain stores, all heads in-block) ----
  float sa[8], da[8];
#pragma unroll
  for (int j = 0; j < 8; ++j) {
    int h = wave * HG + j / JPH;
    int c = (j % JPH) * 16 + ln;
    sa[j] = att_s[h * C + c];
    da[j] = att_d[h * C + c];
  }
#pragma unroll
  for (int hg = 0; hg < HG; ++hg) {
    int h = wave * HG + hg;
#pragma unroll
    for (int i = 0; i < 4; ++i) {
#pragma unroll
      for (int reg = 0; reg < 4; ++reg) {
        float ps = 0.f, pd = 0.f;
#pragma unroll
        for (int jj = 0; jj < JPH; ++jj) {
          int j = hg * JPH + jj;
          ps += acc[i][j][reg] * sa[j];
          pd += acc[i][j][reg] * da[j];
        }
#pragma unroll
        for (int o = 1; o < 16; o <<= 1) { ps += __shfl_xor(ps, o); pd += __shfl_xor(pd, o); }
        int row = m0 + i * 16 + qd * 4 + reg;
        if (ln == 0 && row < M) {
          asrc[row * H + h] = ps;
          adst[row * H + h] = pd;
        }
      }
    }
  }
}

// ---------------- CSR build ------------------------------------------------
__global__ void k_hist(const int* __restrict__ ei, int E, int Etot, int* __restrict__ cnt) {
  int e = blockIdx.x * blockDim.x + threadIdx.x;
  if (e >= Etot) return;
  int d = (e < E) ? ei[E + e] : e - E;
  atomicAdd(&cnt[d], 1);
}

__global__ void k_scan(const int* __restrict__ cnt, int* __restrict__ rowstart, int N) {
  int tid = threadIdx.x;                 // 1024
  int T = (N + 1023) / 1024;
  int base = tid * T;
  int sum = 0;
  for (int i = 0; i < T; ++i) { int j = base + i; if (j < N) sum += cnt[j]; }
  int lane = tid & 63, w = tid >> 6;
  int v = sum;
#pragma unroll
  for (int off = 1; off < 64; off <<= 1) {
    int u = __shfl_up(v, off);
    if (lane >= off) v += u;
  }
  __shared__ int wsum[16];
  if (lane == 63) wsum[w] = v;
  __syncthreads();
  if (tid < 16) {
    int tv = wsum[tid];
#pragma unroll
    for (int off = 1; off < 16; off <<= 1) {
      int u = __shfl_up(tv, off);
      if (tid >= off) tv += u;
    }
    wsum[tid] = tv;
  }
  __syncthreads();
  int wave_prefix = (w == 0) ? 0 : wsum[w - 1];
  int run = wave_prefix + v - sum;       // exclusive prefix for this thread
  for (int i = 0; i < T; ++i) {
    int j = base + i;
    if (j < N) { rowstart[j] = run; run += cnt[j]; }
  }
  if (tid == 1023) rowstart[N] = run;
}

__global__ void k_scatter(const int* __restrict__ ei, int E, int Etot,
                          const int* __restrict__ rowstart, int* __restrict__ cursor,
                          int* __restrict__ csr_src) {
  int e = blockIdx.x * blockDim.x + threadIdx.x;
  if (e >= Etot) return;
  int s = (e < E) ? ei[e] : e - E;
  int d = (e < E) ? ei[E + e] : e - E;
  int pos = atomicAdd(&cursor[d], 1);
  csr_src[rowstart[d] + pos] = s;
}

// -------- wave-per-node gather aggregation, barrier-free -------------------
// Scores at [x*H+h] for BOTH modes now. 2-way edge unroll; csr_src wave-
// broadcast; no LDS, no barriers.
template<int H, int MODE>
__global__ __launch_bounds__(256)
void k_agg(const int* __restrict__ rowstart, const int* __restrict__ csr_src,
           const float* __restrict__ asrc, const float* __restrict__ adst,
           const ushort* __restrict__ xp, ushort* __restrict__ hout,
           float* __restrict__ out2, const float* __restrict__ bias,
           const int* __restrict__ y, const int* __restrict__ msk,
           float* __restrict__ acc2, int N) {
  constexpr int C = HC / H;
  int wave = threadIdx.x >> 6, lane = threadIdx.x & 63;
  int n = blockIdx.x * 4 + wave;
  if (n >= N) return;
  int h = (lane * 8) / C;                // MODE1: lane/8 ; MODE2: lane/16

  float adn = adst[n * H + h];
  float acc[8] = {};
  float wsum = 0.f;
  int beg = rowstart[n], end = rowstart[n + 1];

  int i = beg;
  for (; i + 1 < end; i += 2) {
    int s0 = csr_src[i], s1 = csr_src[i + 1];    // wave-broadcast loads
    float v0 = asrc[s0 * H + h] + adn;
    float v1 = asrc[s1 * H + h] + adn;
    short8 r0 = ((const short8*)xp)[(size_t)s0 * 64 + lane];
    short8 r1 = ((const short8*)xp)[(size_t)s1 * 64 + lane];
    v0 = (v0 > 0.f) ? v0 : 0.2f * v0;
    v1 = (v1 > 0.f) ? v1 : 0.2f * v1;
    float w0 = __expf(v0), w1 = __expf(v1);
#pragma unroll
    for (int k = 0; k < 8; ++k)
      acc[k] += w0 * bf2f((ushort)r0[k]) + w1 * bf2f((ushort)r1[k]);
    wsum += w0 + w1;
  }
  if (i < end) {
    int s0 = csr_src[i];
    float v0 = asrc[s0 * H + h] + adn;
    short8 r0 = ((const short8*)xp)[(size_t)s0 * 64 + lane];
    v0 = (v0 > 0.f) ? v0 : 0.2f * v0;
    float w0 = __expf(v0);
#pragma unroll
    for (int k = 0; k < 8; ++k) acc[k] += w0 * bf2f((ushort)r0[k]);
    wsum += w0;
  }

  float rdn = 1.0f / (wsum + 1e-16f);
#pragma unroll
  for (int k = 0; k < 8; ++k) acc[k] *= rdn;

  if (MODE == 1) {
    short8 rr;
#pragma unroll
    for (int k = 0; k < 8; ++k) {
      float v = acc[k] + bias[lane * 8 + k];
      v = (v > 0.f) ? v : expm1f(v);
      rr[k] = (short)f2bf(v);
    }
    ((short8*)hout)[(size_t)n * 64 + lane] = rr;
  } else {
    // head-mean: lanes l, l+16, l+32, l+48 hold heads 0..3 of col group l&15
    float lg[8];
#pragma unroll
    for (int k = 0; k < 8; ++k) {
      float v = acc[k];
      v += __shfl_xor(v, 16);
      v += __shfl_xor(v, 32);
      lg[k] = v * 0.25f + bias[(lane & 15) * 8 + k];
    }
    if (lane < 16) {
#pragma unroll
      for (int k = 0; k < 8; ++k)
        out2[(size_t)n * NC2 + lane * 8 + k] = lg[k];
    }
    // fused CE (reduce within 16-lane group; groups identical)
    float mx = lg[0];
#pragma unroll
    for (int k = 1; k < 8; ++k) mx = fmaxf(mx, lg[k]);
#pragma unroll
    for (int o = 1; o < 16; o <<= 1) mx = fmaxf(mx, __shfl_xor(mx, o));
    float se = 0.f;
#pragma unroll
    for (int k = 0; k < 8; ++k) se += __expf(lg[k] - mx);
#pragma unroll
    for (int o = 1; o < 16; o <<= 1) se += __shfl_xor(se, o);
    int ty = y[n];
    float myv = lg[0];
#pragma unroll
    for (int k = 1; k < 8; ++k) myv = ((ty & 7) == k) ? lg[k] : myv;
    float tlg = __shfl(myv, ty >> 3);
    if (lane == 0 && msk[n] != 0) {
      float ce = mx + logf(se) - tlg;
      int slot = n & 127;
      atomicAdd(&acc2[slot], ce);
      atomicAdd(&acc2[128 + slot], 1.0f);
    }
  }
}

__global__ void k_final(const float* __restrict__ acc2, float* __restrict__ out0) {
  int tid = threadIdx.x;   // 128 threads
  float ce = acc2[tid], ct = acc2[128 + tid];
#pragma unroll
  for (int o = 32; o > 0; o >>= 1) { ce += __shfl_xor(ce, o); ct += __shfl_xor(ct, o); }
  __shared__ float s[4];
  if ((tid & 63) == 0) { s[(tid >> 6) * 2] = ce; s[(tid >> 6) * 2 + 1] = ct; }
  __syncthreads();
  if (tid == 0) out0[0] = (s[0] + s[2]) / (s[1] + s[3]);
}

extern "C" void kernel_launch(void* const* d_in, const int* in_sizes, int n_in,
                              void* d_out, int out_size, void* d_ws, size_t ws_size,
                              hipStream_t stream) {
  const float* x   = (const float*)d_in[0];
  const int*   ei  = (const int*)d_in[1];
  const int*   y   = (const int*)d_in[2];
  const int*   msk = (const int*)d_in[3];
  const float* W1  = (const float*)d_in[4];
  const float* as1 = (const float*)d_in[5];
  const float* ad1 = (const float*)d_in[6];
  const float* b1  = (const float*)d_in[7];
  const float* W2  = (const float*)d_in[8];
  const float* as2 = (const float*)d_in[9];
  const float* ad2 = (const float*)d_in[10];
  const float* b2  = (const float*)d_in[11];
  float* out = (float*)d_out;

  int N = in_sizes[0] / D_IN;   // 20000
  int E = in_sizes[1] / 2;      // 100000
  int Etot = E + N;             // 120000 (self-loops appended)

  float* ws = (float*)d_ws;
  size_t NF = (size_t)N * HC;
  float* asr1 = ws;                       // N*8  (plain-written in GEMM1)
  float* adt1 = asr1 + (size_t)N * NH1;   // N*8
  float* asr2 = adt1 + (size_t)N * NH1;   // N*4  (plain-written in GEMM2)
  float* adt2 = asr2 + (size_t)N * NH2;   // N*4
  // ---- zero-init region: acc2, cnt, cursor (contiguous) ----
  float* acc2 = adt2 + (size_t)N * NH2;   // 256
  int*   cnt    = (int*)(acc2 + 256);     // N
  int*   cursor = cnt + N;                // N
  size_t zero_bytes = (256 + 2 * (size_t)N) * sizeof(float);
  // ---- fully-written region ----
  int*   rowstart = cursor + N;           // N+1
  int*   csr_src  = rowstart + N + 1;     // Etot
  ushort* xpbf = (ushort*)((((uintptr_t)(csr_src + Etot)) + 15) & ~(uintptr_t)15);
  ushort* Abf = xpbf + NF;                // N*512
  ushort* Wt1 = Abf + NF;                 // 512*512
  ushort* Wt2 = Wt1 + (size_t)D_IN * HC;  // 512*512

  hipMemsetAsync(acc2, 0, zero_bytes, stream);

  // all casts (x, W1^T, W2^T) in one launch
  int n4x = (int)(NF / 4);
  int cast_total = n4x + 2 * D_IN * HC;
  k_cast_all<<<(cast_total + 255) / 256, 256, 0, stream>>>(x, Abf, W1, W2, Wt1, Wt2, n4x);

  // CSR build (shared by both layers)
  k_hist<<<(Etot + 255) / 256, 256, 0, stream>>>(ei, E, Etot, cnt);
  k_scan<<<1, 1024, 0, stream>>>(cnt, rowstart, N);
  k_scatter<<<(Etot + 255) / 256, 256, 0, stream>>>(ei, E, Etot, rowstart, cursor, csr_src);

  int ggrid = (N + GBM - 1) / GBM;          // 313
  int agrid = (N + 3) / 4;                  // 5000

  // ---- layer 1 ----
  k_gemm_bf16<NH1><<<ggrid, 256, 0, stream>>>(Abf, Wt1, xpbf, as1, ad1, asr1, adt1, N);
  k_agg<NH1, 1><<<agrid, 256, 0, stream>>>(rowstart, csr_src, asr1, adt1, xpbf, Abf,
                                           nullptr, b1, nullptr, nullptr, nullptr, N);

  // ---- layer 2 ----
  k_gemm_bf16<NH2><<<ggrid, 256, 0, stream>>>(Abf, Wt2, xpbf, as2, ad2, asr2, adt2, N);
  k_agg<NH2, 2><<<agrid, 256, 0, stream>>>(rowstart, csr_src, asr2, adt2, xpbf, nullptr,
                                           out + 1, b2, y, msk, acc2, N);

  // ---- epilogue: loss ----
  k_final<<<1, 128, 0, stream>>>(acc2, out);
}

// Round 14
// 287.520 us; speedup vs baseline: 1.2835x; 1.2835x over previous
//
#include <hip/hip_runtime.h>
#include <cmath>

#define D_IN 512
#define HC   512   // H1*C1 == H2*C2 == D_IN
#define NH1  8
#define NC1  64
#define NH2  4
#define NC2  128
#define BM 128
#define BN 128
#define BK 64

typedef __attribute__((ext_vector_type(8))) short short8;
typedef __attribute__((ext_vector_type(4))) float f32x4;

__device__ inline ushort f2bf(float f) {
  unsigned u = __float_as_uint(f);
  return (ushort)((u + 0x7FFFu + ((u >> 16) & 1u)) >> 16);
}
__device__ inline float bf2f(ushort b) { return __uint_as_float(((unsigned)b) << 16); }

// ---------- all input casts in one launch ----------------------------------
__global__ void k_cast_all(const float* __restrict__ x, ushort* __restrict__ Abf,
                           const float* __restrict__ W1, const float* __restrict__ W2,
                           ushort* __restrict__ Wt1, ushort* __restrict__ Wt2, int n4x) {
  const int KN = D_IN * HC;
  int i = blockIdx.x * blockDim.x + threadIdx.x;
  if (i < n4x) {
    float4 v = ((const float4*)x)[i];
    ushort4 r = { f2bf(v.x), f2bf(v.y), f2bf(v.z), f2bf(v.w) };
    ((ushort4*)Abf)[i] = r;
  } else {
    int idx = i - n4x;
    if (idx >= 2 * KN) return;
    const float* W = (idx < KN) ? W1 : W2;
    ushort* Wt = (idx < KN) ? Wt1 : Wt2;
    int j = (idx < KN) ? idx : idx - KN;
    int n = j / D_IN, k = j - n * D_IN;
    Wt[j] = f2bf(W[(size_t)k * HC + n]);
  }
}

// ---------- bf16 MFMA GEMM, BK=64 (8 loads/thread/iter), fused att epilogue -
// LDS per K-half (32 cols) in fragment order: slot s=(rowgrp)*4+kchunk,
// addr=(s*16+ln)*8 ushorts; staging thread t -> LDS offset t*8 per round
// (wave-uniform base + lane*16B as global_load_lds requires); ds_read is
// stride-1 across lanes -> conflict-free (verified R9: SQ_LDS_BANK_CONFLICT=0).
// BK=64 doubles in-flight bytes per barrier cycle and halves barrier count.
// Att epilogue: plain stores only. H=8 (C=64): one slot per (row,h).
// H=4 (C=128): two partial slots per (row,h): [(row*4+h)*2+sub], sub=col64-idx.
// NOTE (R13): do NOT trade occupancy/grid for traffic here — BN=512 variant
// (224 VGPR, 313 blocks) regressed 42->79 us despite 3.5x lower FETCH.
template<int H>
__global__ void k_gemm_bf16(const ushort* __restrict__ A, const ushort* __restrict__ Bt,
                            ushort* __restrict__ Cbf,
                            const float* __restrict__ att_s, const float* __restrict__ att_d,
                            float* __restrict__ asrc, float* __restrict__ adst, int M) {
  constexpr int C = HC / H;
  __shared__ __align__(16) ushort As[BM * BK];   // 16 KB, two 8KB K-halves
  __shared__ __align__(16) ushort Bs[BN * BK];   // 16 KB
  int t = threadIdx.x;
  int m0 = blockIdx.y * BM;
  int n0 = blockIdx.x * BN;
  int wave = t >> 6, lane = t & 63;
  int ln = lane & 15, qd = lane >> 4;
  int wm = (wave >> 1) * 64, wn = (wave & 1) * 64;

  f32x4 acc[4][4] = {};

  int g = t >> 6, ct = (t >> 4) & 3, lt = t & 15;
  int rA0 = m0 + g * 16 + lt;      if (rA0 > M - 1) rA0 = M - 1;
  int rA1 = m0 + 64 + g * 16 + lt; if (rA1 > M - 1) rA1 = M - 1;
  const ushort* gA0 = A + (size_t)rA0 * D_IN + ct * 8;
  const ushort* gA1 = A + (size_t)rA1 * D_IN + ct * 8;
  const ushort* gB0 = Bt + (size_t)(n0 + g * 16 + lt) * D_IN + ct * 8;
  const ushort* gB1 = Bt + (size_t)(n0 + 64 + g * 16 + lt) * D_IN + ct * 8;

  for (int k0 = 0; k0 < D_IN; k0 += BK) {
    __syncthreads();
#pragma unroll
    for (int h = 0; h < 2; ++h) {
      int ko = k0 + h * 32;
      int lo = h * 4096;
      __builtin_amdgcn_global_load_lds(
          (const __attribute__((address_space(1))) void*)(gA0 + ko),
          (__attribute__((address_space(3))) void*)(As + lo + t * 8), 16, 0, 0);
      __builtin_amdgcn_global_load_lds(
          (const __attribute__((address_space(1))) void*)(gA1 + ko),
          (__attribute__((address_space(3))) void*)(As + lo + 2048 + t * 8), 16, 0, 0);
      __builtin_amdgcn_global_load_lds(
          (const __attribute__((address_space(1))) void*)(gB0 + ko),
          (__attribute__((address_space(3))) void*)(Bs + lo + t * 8), 16, 0, 0);
      __builtin_amdgcn_global_load_lds(
          (const __attribute__((address_space(1))) void*)(gB1 + ko),
          (__attribute__((address_space(3))) void*)(Bs + lo + 2048 + t * 8), 16, 0, 0);
    }
    __syncthreads();
#pragma unroll
    for (int h = 0; h < 2; ++h) {
      int lo = h * 4096;
      short8 a[4], bb[4];
#pragma unroll
      for (int i = 0; i < 4; ++i)
        a[i] = *(const short8*)&As[lo + (((wave >> 1) * 4 + i) * 4 + qd) * 128 + ln * 8];
#pragma unroll
      for (int j = 0; j < 4; ++j)
        bb[j] = *(const short8*)&Bs[lo + (((wave & 1) * 4 + j) * 4 + qd) * 128 + ln * 8];
#pragma unroll
      for (int i = 0; i < 4; ++i)
#pragma unroll
        for (int j = 0; j < 4; ++j)
          acc[i][j] = __builtin_amdgcn_mfma_f32_16x16x32_bf16(a[i], bb[j], acc[i][j], 0, 0, 0);
    }
  }

  // ---- C store (C/D layout: col = ln, row = qd*4 + reg) ----
#pragma unroll
  for (int i = 0; i < 4; ++i) {
#pragma unroll
    for (int reg = 0; reg < 4; ++reg) {
      int row = m0 + wm + i * 16 + qd * 4 + reg;
      if (row >= M) continue;
#pragma unroll
      for (int j = 0; j < 4; ++j)
        Cbf[(size_t)row * HC + n0 + wn + j * 16 + ln] = f2bf(acc[i][j][reg]);
    }
  }

  // ---- fused attention scores (plain stores only) ----
  int colbase = n0 + wn;         // multiple of 64
  int h = colbase / C;
  float sa[4], da[4];
#pragma unroll
  for (int j = 0; j < 4; ++j) {
    int c = (colbase % C) + j * 16 + ln;
    sa[j] = att_s[h * C + c];
    da[j] = att_d[h * C + c];
  }
#pragma unroll
  for (int i = 0; i < 4; ++i) {
#pragma unroll
    for (int reg = 0; reg < 4; ++reg) {
      float ps = acc[i][0][reg] * sa[0] + acc[i][1][reg] * sa[1]
               + acc[i][2][reg] * sa[2] + acc[i][3][reg] * sa[3];
      float pd = acc[i][0][reg] * da[0] + acc[i][1][reg] * da[1]
               + acc[i][2][reg] * da[2] + acc[i][3][reg] * da[3];
#pragma unroll
      for (int o = 1; o < 16; o <<= 1) { ps += __shfl_xor(ps, o); pd += __shfl_xor(pd, o); }
      int row = m0 + wm + i * 16 + qd * 4 + reg;
      if (ln == 0 && row < M) {
        if (C == 64) {
          asrc[row * H + h] = ps; adst[row * H + h] = pd;
        } else {
          int sub = (colbase >> 6) & 1;
          asrc[(row * H + h) * 2 + sub] = ps;
          adst[(row * H + h) * 2 + sub] = pd;
        }
      }
    }
  }
}

// ---------------- CSR build ------------------------------------------------
__global__ void k_hist(const int* __restrict__ ei, int E, int Etot, int* __restrict__ cnt) {
  int e = blockIdx.x * blockDim.x + threadIdx.x;
  if (e >= Etot) return;
  int d = (e < E) ? ei[E + e] : e - E;
  atomicAdd(&cnt[d], 1);
}

// single-block scan, thread-serial + shuffle (2 barriers total)
__global__ void k_scan(const int* __restrict__ cnt, int* __restrict__ rowstart, int N) {
  int tid = threadIdx.x;                 // 1024
  int T = (N + 1023) / 1024;
  int base = tid * T;
  int sum = 0;
  for (int i = 0; i < T; ++i) { int j = base + i; if (j < N) sum += cnt[j]; }
  int lane = tid & 63, w = tid >> 6;
  int v = sum;
#pragma unroll
  for (int off = 1; off < 64; off <<= 1) {
    int u = __shfl_up(v, off);
    if (lane >= off) v += u;
  }
  __shared__ int wsum[16];
  if (lane == 63) wsum[w] = v;
  __syncthreads();
  if (tid < 16) {
    int tv = wsum[tid];
#pragma unroll
    for (int off = 1; off < 16; off <<= 1) {
      int u = __shfl_up(tv, off);
      if (tid >= off) tv += u;
    }
    wsum[tid] = tv;
  }
  __syncthreads();
  int wave_prefix = (w == 0) ? 0 : wsum[w - 1];
  int run = wave_prefix + v - sum;       // exclusive prefix for this thread
  for (int i = 0; i < T; ++i) {
    int j = base + i;
    if (j < N) { rowstart[j] = run; run += cnt[j]; }
  }
  if (tid == 1023) rowstart[N] = run;
}

__global__ void k_scatter(const int* __restrict__ ei, int E, int Etot,
                          const int* __restrict__ rowstart, int* __restrict__ cursor,
                          int* __restrict__ csr_src) {
  int e = blockIdx.x * blockDim.x + threadIdx.x;
  if (e >= Etot) return;
  int s = (e < E) ? ei[e] : e - E;
  int d = (e < E) ? ei[E + e] : e - E;
  int pos = atomicAdd(&cursor[d], 1);
  csr_src[rowstart[d] + pos] = s;
}

// -------- gather aggregation with inline softmax, 128 thr/node -------------
// 2-way edge unroll for MLP. No max-subtraction (scores O(1), fp32-safe).
// MODE 1 (H=8): scores at [x*H+h]; hout = bf16(elu(sum/den + b)).
// MODE 2 (H=4): scores are 2 partials at [(x*H+h)*2+{0,1}];
//               out[n,c] = mean_h + b[c] -> fused CE into acc2.
template<int H, int MODE>
__global__ void k_agg(const int* __restrict__ rowstart, const int* __restrict__ csr_src,
                      const float* __restrict__ asrc, const float* __restrict__ adst,
                      const ushort* __restrict__ xp, ushort* __restrict__ hout,
                      float* __restrict__ out2, const float* __restrict__ bias,
                      const int* __restrict__ y, const int* __restrict__ msk,
                      float* __restrict__ acc2, int N) {
  int n = blockIdx.x;
  int tid = threadIdx.x;                 // 128
  constexpr int C = HC / H;
  int h = (tid * 4) / C;
  int beg = rowstart[n], end = rowstart[n + 1];

  __shared__ int   s_src[32];
  __shared__ float s_out[512];

  float adn = (MODE == 1) ? adst[n * H + h]
                          : adst[(n * H + h) * 2] + adst[(n * H + h) * 2 + 1];
  float ax = 0.f, ay = 0.f, az = 0.f, aw = 0.f, wsum = 0.f;

#define SCORE(s) ((MODE == 1) ? asrc[(s) * H + h] \
                              : asrc[((s) * H + h) * 2] + asrc[((s) * H + h) * 2 + 1])

  for (int c0 = beg; c0 < end; c0 += 32) {
    int len = end - c0; if (len > 32) len = 32;
    __syncthreads();
    if (tid < len) s_src[tid] = csr_src[c0 + tid];
    __syncthreads();
    int i = 0;
    for (; i + 1 < len; i += 2) {
      int s0 = s_src[i], s1 = s_src[i + 1];
      float v0 = SCORE(s0) + adn;
      float v1 = SCORE(s1) + adn;
      ushort4 a0 = ((const ushort4*)xp)[(size_t)s0 * 128 + tid];
      ushort4 a1 = ((const ushort4*)xp)[(size_t)s1 * 128 + tid];
      v0 = (v0 > 0.f) ? v0 : 0.2f * v0;
      v1 = (v1 > 0.f) ? v1 : 0.2f * v1;
      float w0 = __expf(v0), w1 = __expf(v1);
      ax += w0 * bf2f(a0.x) + w1 * bf2f(a1.x);
      ay += w0 * bf2f(a0.y) + w1 * bf2f(a1.y);
      az += w0 * bf2f(a0.z) + w1 * bf2f(a1.z);
      aw += w0 * bf2f(a0.w) + w1 * bf2f(a1.w);
      wsum += w0 + w1;
    }
    if (i < len) {
      int s0 = s_src[i];
      float v0 = SCORE(s0) + adn;
      ushort4 a0 = ((const ushort4*)xp)[(size_t)s0 * 128 + tid];
      v0 = (v0 > 0.f) ? v0 : 0.2f * v0;
      float w0 = __expf(v0);
      ax += w0 * bf2f(a0.x); ay += w0 * bf2f(a0.y);
      az += w0 * bf2f(a0.z); aw += w0 * bf2f(a0.w);
      wsum += w0;
    }
  }
#undef SCORE
  float rdn = 1.0f / (wsum + 1e-16f);
  ax *= rdn; ay *= rdn; az *= rdn; aw *= rdn;

  if (MODE == 1) {
    int hc = tid * 4;
    float v0 = ax + bias[hc], v1 = ay + bias[hc + 1];
    float v2 = az + bias[hc + 2], v3 = aw + bias[hc + 3];
    v0 = (v0 > 0.f) ? v0 : expm1f(v0);
    v1 = (v1 > 0.f) ? v1 : expm1f(v1);
    v2 = (v2 > 0.f) ? v2 : expm1f(v2);
    v3 = (v3 > 0.f) ? v3 : expm1f(v3);
    ushort4 rr = { f2bf(v0), f2bf(v1), f2bf(v2), f2bf(v3) };
    ((ushort4*)hout)[(size_t)n * 128 + tid] = rr;
  } else {
    int hc = tid * 4;
    s_out[hc] = ax; s_out[hc + 1] = ay; s_out[hc + 2] = az; s_out[hc + 3] = aw;
    __syncthreads();
    if (tid < 32) {
#pragma unroll
      for (int k = 0; k < 4; ++k) {
        int c = tid * 4 + k;
        float sum = s_out[c] + s_out[128 + c] + s_out[256 + c] + s_out[384 + c];
        float lg = sum * 0.25f + bias[c];
        out2[(size_t)n * NC2 + c] = lg;
        s_out[c] = lg;                  // disjoint per thread, safe
      }
    }
    __syncthreads();
    // fused CE over the 128 logits (2 waves)
    float lv = s_out[tid];
    int lane = tid & 63, wv = tid >> 6;
    float mx = lv;
#pragma unroll
    for (int o = 32; o > 0; o >>= 1) mx = fmaxf(mx, __shfl_xor(mx, o));
    if (lane == 0) s_out[256 + wv] = mx;
    __syncthreads();
    mx = fmaxf(s_out[256], s_out[257]);
    float e = __expf(lv - mx);
#pragma unroll
    for (int o = 32; o > 0; o >>= 1) e += __shfl_xor(e, o);
    if (lane == 0) s_out[260 + wv] = e;
    __syncthreads();
    if (tid == 0 && msk[n] != 0) {
      float se = s_out[260] + s_out[261];
      float ce = mx + logf(se) - s_out[y[n]];
      int slot = n & 127;
      atomicAdd(&acc2[slot], ce);
      atomicAdd(&acc2[128 + slot], 1.0f);
    }
  }
}

__global__ void k_final(const float* __restrict__ acc2, float* __restrict__ out0) {
  int tid = threadIdx.x;   // 128 threads
  float ce = acc2[tid], ct = acc2[128 + tid];
#pragma unroll
  for (int o = 32; o > 0; o >>= 1) { ce += __shfl_xor(ce, o); ct += __shfl_xor(ct, o); }
  __shared__ float s[4];
  if ((tid & 63) == 0) { s[(tid >> 6) * 2] = ce; s[(tid >> 6) * 2 + 1] = ct; }
  __syncthreads();
  if (tid == 0) out0[0] = (s[0] + s[2]) / (s[1] + s[3]);
}

extern "C" void kernel_launch(void* const* d_in, const int* in_sizes, int n_in,
                              void* d_out, int out_size, void* d_ws, size_t ws_size,
                              hipStream_t stream) {
  const float* x   = (const float*)d_in[0];
  const int*   ei  = (const int*)d_in[1];
  const int*   y   = (const int*)d_in[2];
  const int*   msk = (const int*)d_in[3];
  const float* W1  = (const float*)d_in[4];
  const float* as1 = (const float*)d_in[5];
  const float* ad1 = (const float*)d_in[6];
  const float* b1  = (const float*)d_in[7];
  const float* W2  = (const float*)d_in[8];
  const float* as2 = (const float*)d_in[9];
  const float* ad2 = (const float*)d_in[10];
  const float* b2  = (const float*)d_in[11];
  float* out = (float*)d_out;

  int N = in_sizes[0] / D_IN;   // 20000
  int E = in_sizes[1] / 2;      // 100000
  int Etot = E + N;             // 120000 (self-loops appended)

  float* ws = (float*)d_ws;
  size_t NF = (size_t)N * HC;
  float* asr1 = ws;                       // N*8  (plain-written in GEMM1)
  float* adt1 = asr1 + (size_t)N * NH1;   // N*8
  float* asr2 = adt1 + (size_t)N * NH1;   // N*8  (partials, plain-written GEMM2)
  float* adt2 = asr2 + (size_t)N * 2 * NH2; // N*8
  // ---- zero-init region: acc2, cnt, cursor (contiguous) ----
  float* acc2 = adt2 + (size_t)N * 2 * NH2; // 256
  int*   cnt    = (int*)(acc2 + 256);     // N
  int*   cursor = cnt + N;                // N
  size_t zero_bytes = (256 + 2 * (size_t)N) * sizeof(float);
  // ---- fully-written region ----
  int*   rowstart = cursor + N;           // N+1
  int*   csr_src  = rowstart + N + 1;     // Etot
  ushort* xpbf = (ushort*)((((uintptr_t)(csr_src + Etot)) + 15) & ~(uintptr_t)15);
  ushort* Abf = xpbf + NF;                // N*512
  ushort* Wt1 = Abf + NF;                 // 512*512
  ushort* Wt2 = Wt1 + (size_t)D_IN * HC;  // 512*512

  hipMemsetAsync(acc2, 0, zero_bytes, stream);

  // all casts (x, W1^T, W2^T) in one launch
  int n4x = (int)(NF / 4);
  int cast_total = n4x + 2 * D_IN * HC;
  k_cast_all<<<(cast_total + 255) / 256, 256, 0, stream>>>(x, Abf, W1, W2, Wt1, Wt2, n4x);

  // CSR build (shared by both layers)
  k_hist<<<(Etot + 255) / 256, 256, 0, stream>>>(ei, E, Etot, cnt);
  k_scan<<<1, 1024, 0, stream>>>(cnt, rowstart, N);
  k_scatter<<<(Etot + 255) / 256, 256, 0, stream>>>(ei, E, Etot, rowstart, cursor, csr_src);

  dim3 ggrid(HC / BN, (N + BM - 1) / BM);   // 4 x 157

  // ---- layer 1 ----
  k_gemm_bf16<NH1><<<ggrid, 256, 0, stream>>>(Abf, Wt1, xpbf, as1, ad1, asr1, adt1, N);
  k_agg<NH1, 1><<<N, 128, 0, stream>>>(rowstart, csr_src, asr1, adt1, xpbf, Abf,
                                       nullptr, b1, nullptr, nullptr, nullptr, N);

  // ---- layer 2 ----
  k_gemm_bf16<NH2><<<ggrid, 256, 0, stream>>>(Abf, Wt2, xpbf, as2, ad2, asr2, adt2, N);
  k_agg<NH2, 2><<<N, 128, 0, stream>>>(rowstart, csr_src, asr2, adt2, xpbf, nullptr,
                                       out + 1, b2, y, msk, acc2, N);

  // ---- epilogue: loss ----
  k_final<<<1, 128, 0, stream>>>(acc2, out);
}